// Round 2
// baseline (632.396 us; speedup 1.0000x reference)
//
#include <hip/hip_runtime.h>
#include <math.h>

#define B_ 256
#define S_ 6
#define C_ 80
#define F_ 2048
#define E_ 300
#define H_ 1024
#define EPS_ 1e-7f
#define DEPS_ 1e-8f
#define LEAK_ 0.2f

// ---- ws layout (float offsets) ----
#define IMG_OFF   0u          // img_feats [256,2048]            = 524288
#define Z_OFF     524288u     // Z = inp@W1 [80,1024]            = 81920
#define ADJA_OFF  644608u     // adjA [6,80,80]                  = 38400
#define G_OFF     683008u     // g = LReLU(adjA@Z) [6,80,1024]   = 491520
#define PART_OFF  1174528u    // u partials [8][256,1024]        = 2097152
#define IDS_OFF   5368832u    // ids [256] (int)

// ---- d_out layout (float offsets) ----
#define OUT0_OFF 0            // output [256,80]
#define PROB_OFF 20480        // scene_probs [256,6]
#define SEN_OUT  22016        // sample_en
#define BEN_OUT  22017        // batch_en
#define CMTS_OFF 22018        // comats [256,80,80]

// L1: fused. Blocks [0,320): Z = inp@W1 (small, scheduled first so it hides
// under the 411MB x-scan). Blocks [320, 320+131072): global max over 14x14.
__global__ __launch_bounds__(256) void k_pool_z(const float* __restrict__ x,
                                                float* __restrict__ img,
                                                const float* __restrict__ inp,
                                                const float* __restrict__ W1,
                                                float* __restrict__ Z) {
    if (blockIdx.x < 320) {
        int c = blockIdx.x >> 2;
        int h = ((blockIdx.x & 3) << 8) + threadIdx.x;
        float acc = 0.f;
        for (int e = 0; e < E_; e++) acc += inp[c * E_ + e] * W1[e * H_ + h];
        Z[c * H_ + h] = acc;
    } else {
        int pair = (blockIdx.x - 320) * 4 + (threadIdx.x >> 6);
        int lane = threadIdx.x & 63;
        const float4* xp = (const float4*)x + (size_t)pair * 49;
        float m = -INFINITY;
        if (lane < 49) {
            float4 v = xp[lane];
            m = fmaxf(fmaxf(v.x, v.y), fmaxf(v.z, v.w));
        }
#pragma unroll
        for (int off = 32; off >= 1; off >>= 1) m = fmaxf(m, __shfl_xor(m, off));
        if (lane == 0) img[pair] = m;
    }
}

// L2: fused. Blocks [0,256): scene softmax/argmax per b. Blocks [256,384):
// split-K=8 u-GEMM (u = img @ W2^T), 128x128 tile, 8x8 per-thread acc.
__global__ __launch_bounds__(256) void k_scene_ugemm(const float* __restrict__ img,
                                                     const float* __restrict__ Ws,
                                                     const float* __restrict__ W2,
                                                     float* __restrict__ probs_out,
                                                     int* __restrict__ ids,
                                                     float* __restrict__ part) {
    __shared__ float sm[2 * 16 * 132];   // 16.9 KB; scene branch uses 6*256 of it
    int tid = threadIdx.x;
    if (blockIdx.x < 256) {
        float (*red)[256] = (float(*)[256])sm;
        int b = blockIdx.x;
        float acc[6] = {0, 0, 0, 0, 0, 0};
#pragma unroll
        for (int i = 0; i < 8; i++) {
            int f = tid + i * 256;
            float a = img[b * F_ + f];
#pragma unroll
            for (int s = 0; s < 6; s++) acc[s] += a * Ws[f * 6 + s];
        }
        for (int s = 0; s < 6; s++) red[s][tid] = acc[s];
        __syncthreads();
        for (int off = 128; off > 0; off >>= 1) {
            if (tid < off)
                for (int s = 0; s < 6; s++) red[s][tid] += red[s][tid + off];
            __syncthreads();
        }
        if (tid == 0) {
            float sc[6], mx = -INFINITY;
            for (int s = 0; s < 6; s++) { sc[s] = red[s][0]; mx = fmaxf(mx, sc[s]); }
            float sum = 0.f;
            for (int s = 0; s < 6; s++) { sc[s] = expf(sc[s] - mx); sum += sc[s]; }
            float inv = 1.0f / sum;
            int best = 0; float bv = -1.f;
            for (int s = 0; s < 6; s++) {
                float p = sc[s] * inv;
                probs_out[b * 6 + s] = p;
                if (p > bv) { bv = p; best = s; }
            }
            ids[b] = best;
        }
    } else {
        float* As = sm;
        float* Bs = sm + 16 * 132;
        int t = blockIdx.x - 256;
        int bx = t & 7, by = (t >> 3) & 1, bz = t >> 4;   // bz in [0,8)
        int m0 = by * 128, h0 = bx * 128;
        int kbase = bz * 256;
        float acc[8][8];
#pragma unroll
        for (int i = 0; i < 8; i++)
#pragma unroll
            for (int j = 0; j < 8; j++) acc[i][j] = 0.f;
        int r0 = (tid >> 4) << 3, c0 = (tid & 15) << 3;
        for (int st = 0; st < 16; st++) {
            int kc = kbase + st * 16;
#pragma unroll
            for (int l = 0; l < 2; l++) {
                int fid = tid + (l << 8);
                int r = fid >> 2, kq = fid & 3;
                float4 av = *(const float4*)(img + (size_t)(m0 + r) * 2048 + kc + (kq << 2));
                float4 bv = *(const float4*)(W2 + (size_t)(h0 + r) * 2048 + kc + (kq << 2));
                int kk = kq << 2;
                As[(kk + 0) * 132 + r] = av.x; As[(kk + 1) * 132 + r] = av.y;
                As[(kk + 2) * 132 + r] = av.z; As[(kk + 3) * 132 + r] = av.w;
                Bs[(kk + 0) * 132 + r] = bv.x; Bs[(kk + 1) * 132 + r] = bv.y;
                Bs[(kk + 2) * 132 + r] = bv.z; Bs[(kk + 3) * 132 + r] = bv.w;
            }
            __syncthreads();
#pragma unroll
            for (int k = 0; k < 16; k++) {
                float4 a0 = *(const float4*)&As[k * 132 + r0];
                float4 a1 = *(const float4*)&As[k * 132 + r0 + 4];
                float4 b0 = *(const float4*)&Bs[k * 132 + c0];
                float4 b1 = *(const float4*)&Bs[k * 132 + c0 + 4];
                float ar[8] = {a0.x, a0.y, a0.z, a0.w, a1.x, a1.y, a1.z, a1.w};
                float br[8] = {b0.x, b0.y, b0.z, b0.w, b1.x, b1.y, b1.z, b1.w};
#pragma unroll
                for (int i = 0; i < 8; i++)
#pragma unroll
                    for (int j = 0; j < 8; j++) acc[i][j] += ar[i] * br[j];
            }
            __syncthreads();
        }
        float* pu = part + (size_t)bz * 262144;
#pragma unroll
        for (int i = 0; i < 8; i++) {
            int row = m0 + r0 + i;
            float4 v0 = {acc[i][0], acc[i][1], acc[i][2], acc[i][3]};
            float4 v1 = {acc[i][4], acc[i][5], acc[i][6], acc[i][7]};
            *(float4*)(pu + (size_t)row * 1024 + h0 + c0) = v0;
            *(float4*)(pu + (size_t)row * 1024 + h0 + c0 + 4) = v1;
        }
    }
}

// L3: graph kernel. Every block recomputes the (tiny) updated+normalized
// comatrix of its scene in LDS — no global comat, no 6-block serialization.
//   blocks [0,480):   (s,c): adjA row c of scene s (written for k_out) and
//                     g[s,c,:] = LeakyReLU(adjA_row @ Z)
//   blocks [480,736): b: cmts[b] = normalized comat of scene ids[b]
//   block 736:        entropy finalization from probs
__global__ __launch_bounds__(256) void k_graph(const float* __restrict__ y,
                                               const float* __restrict__ cm_in,
                                               const int* __restrict__ ids,
                                               const float* __restrict__ Z,
                                               const float* __restrict__ probs,
                                               float* __restrict__ adjA,
                                               float* __restrict__ g,
                                               float* __restrict__ cmts,
                                               float* __restrict__ o_sen,
                                               float* __restrict__ o_ben) {
    int tid = threadIdx.x;
    if (blockIdx.x == 736) {
        if (tid < 64) {
            float lent = 0.f;
            float lp[6] = {0, 0, 0, 0, 0, 0};
            for (int i = 0; i < 4; i++) {
                int b = tid * 4 + i;
#pragma unroll
                for (int s = 0; s < 6; s++) {
                    float p = probs[b * 6 + s];
                    lp[s] += p;
                    lent -= p * logf(p + EPS_);
                }
            }
#pragma unroll
            for (int off = 32; off >= 1; off >>= 1) {
                lent += __shfl_xor(lent, off);
#pragma unroll
                for (int s = 0; s < 6; s++) lp[s] += __shfl_xor(lp[s], off);
            }
            if (tid == 0) {
                *o_sen = lent / 256.0f;
                float ent = 0.f;
                for (int s = 0; s < 6; s++) {
                    float q = lp[s] / 256.0f;
                    ent -= q * logf(q + EPS_);
                }
                float invS = 1.0f / 6.0f;
                float men = -6.0f * (invS * logf(invS + EPS_));
                *o_ben = (men - ent) * 100.0f;
            }
        }
        return;
    }
    __shared__ unsigned long long colq[80][4];
    __shared__ float cm[6400];
    __shared__ float diag[80], Dn[80], arow[80];
    __shared__ int idsL[256];
    bool isG = blockIdx.x < 480;
    int s, c = 0, b = 0;
    if (isG) { s = blockIdx.x / 80; c = blockIdx.x % 80; }
    else { b = blockIdx.x - 480; s = ids[b]; }
    idsL[tid] = ids[tid];
    __syncthreads();
    int wave = tid >> 6, lane = tid & 63;
    bool ok = (idsL[tid] == s);
    for (int i = 0; i < 80; i++) {
        unsigned long long mk = __ballot(ok && (y[tid * 80 + i] != 0.0f));
        if (lane == 0) colq[i][wave] = mk;
    }
    __syncthreads();
    for (int p = tid; p < 6400; p += 256) {
        int i = p / 80, j = p - i * 80;
        int cnt = 0;
#pragma unroll
        for (int w = 0; w < 4; w++) cnt += __popcll(colq[i][w] & colq[j][w]);
        cm[p] = cm_in[s * 6400 + p] + (float)cnt;
    }
    __syncthreads();
    if (tid < 80) diag[tid] = cm[tid * 81];
    __syncthreads();
    for (int p = tid; p < 6400; p += 256) {
        int i = p / 80, j = p - i * 80;
        cm[p] = (i == j) ? 1.0f : cm[p] / (diag[i] + DEPS_);
    }
    __syncthreads();
    if (!isG) {
        const float2* src = (const float2*)cm;
        float2* dst = (float2*)(cmts + (size_t)b * 6400);
        for (int i = tid; i < 3200; i += 256) dst[i] = src[i];
        return;
    }
    if (tid < 80) {
        float rs = 0.f;
        for (int j = 0; j < 80; j++) rs += cm[tid * 80 + j];
        Dn[tid] = 1.0f / sqrtf(rs);
    }
    __syncthreads();
    if (tid < 80) {
        float v = Dn[c] * cm[tid * 80 + c] * Dn[tid];
        arow[tid] = v;
        adjA[(s * 80 + c) * 80 + tid] = v;
    }
    __syncthreads();
    const float4* Z4 = (const float4*)Z;
    float4 acc = {0, 0, 0, 0};
    for (int j = 0; j < 80; j++) {
        float a = arow[j];
        float4 z = Z4[j * 256 + tid];
        acc.x += a * z.x; acc.y += a * z.y; acc.z += a * z.z; acc.w += a * z.w;
    }
    acc.x = acc.x > 0.f ? acc.x : LEAK_ * acc.x;
    acc.y = acc.y > 0.f ? acc.y : LEAK_ * acc.y;
    acc.z = acc.z > 0.f ? acc.z : LEAK_ * acc.z;
    acc.w = acc.w > 0.f ? acc.w : LEAK_ * acc.w;
    ((float4*)g)[(s * 80 + c) * 256 + tid] = acc;
}

// L4: per-b: u[b] = sum of 8 partials; t = g[s]@u; out[b] = adjA[s]@t.
__global__ __launch_bounds__(320) void k_out(const float* __restrict__ part,
                                             const float* __restrict__ g,
                                             const float* __restrict__ adjA,
                                             const int* __restrict__ ids,
                                             float* __restrict__ out0) {
    __shared__ float ul[1024];
    __shared__ float tp[320];
    __shared__ float tv[80];
    int b = blockIdx.x, tid = threadIdx.x;
    int s = ids[b];
    for (int h = tid; h < 1024; h += 320) {
        float a = 0.f;
#pragma unroll
        for (int z = 0; z < 8; z++) a += part[z * 262144 + b * 1024 + h];
        ul[h] = a;
    }
    __syncthreads();
    int c = tid >> 2, q = tid & 3;
    const float4* gp = (const float4*)(g + (s * 80 + c) * 1024 + q * 256);
    const float4* up = (const float4*)(ul + q * 256);
    float a = 0.f;
    for (int k = 0; k < 64; k++) {
        float4 gv = gp[k];
        float4 uv = up[k];
        a += gv.x * uv.x + gv.y * uv.y + gv.z * uv.z + gv.w * uv.w;
    }
    tp[tid] = a;
    __syncthreads();
    if (tid < 80) tv[tid] = tp[tid * 4] + tp[tid * 4 + 1] + tp[tid * 4 + 2] + tp[tid * 4 + 3];
    __syncthreads();
    if (tid < 80) {
        const float* ar = adjA + (s * 80 + tid) * 80;
        float o = 0.f;
        for (int j = 0; j < 80; j++) o += ar[j] * tv[j];
        out0[b * 80 + tid] = o;
    }
}

extern "C" void kernel_launch(void* const* d_in, const int* in_sizes, int n_in,
                              void* d_out, int out_size, void* d_ws, size_t ws_size,
                              hipStream_t stream) {
    const float* x    = (const float*)d_in[0];
    const float* inp  = (const float*)d_in[1];
    const float* y    = (const float*)d_in[2];
    const float* cmin = (const float*)d_in[3];
    const float* Ws   = (const float*)d_in[4];
    const float* W1   = (const float*)d_in[5];
    const float* W2   = (const float*)d_in[6];
    float* out = (float*)d_out;
    float* W = (float*)d_ws;

    float* img   = W + IMG_OFF;
    float* Z     = W + Z_OFF;
    float* adjA  = W + ADJA_OFF;
    float* g     = W + G_OFF;
    float* part  = W + PART_OFF;
    int*   ids   = (int*)(W + IDS_OFF);

    k_pool_z<<<131392, 256, 0, stream>>>(x, img, inp, W1, Z);
    k_scene_ugemm<<<384, 256, 0, stream>>>(img, Ws, W2, out + PROB_OFF, ids, part);
    k_graph<<<737, 256, 0, stream>>>(y, cmin, ids, Z, out + PROB_OFF, adjA, g,
                                     out + CMTS_OFF, out + SEN_OUT, out + BEN_OUT);
    k_out<<<256, 320, 0, stream>>>(part, g, adjA, ids, out + OUT0_OFF);
}

// Round 3
// 617.332 us; speedup vs baseline: 1.0244x; 1.0244x over previous
//
#include <hip/hip_runtime.h>
#include <math.h>

#define B_ 256
#define S_ 6
#define C_ 80
#define F_ 2048
#define E_ 300
#define H_ 1024
#define EPS_ 1e-7f
#define DEPS_ 1e-8f
#define LEAK_ 0.2f

// ---- ws layout (float offsets) ----
#define IMG_OFF   0u          // img_feats [256,2048]            = 524288
#define Z_OFF     524288u     // Z = inp@W1 [80,1024]            = 81920
#define ADJA_OFF  644608u     // adjA [6,80,80]                  = 38400
#define G_OFF     683008u     // g = LReLU(adjA@Z) [6,80,1024]   = 491520
#define PART_OFF  1174528u    // u partials [8][256,1024]        = 2097152
#define IDS_OFF   5368832u    // ids [256] (int)                 = 256
#define YM_OFF    5369088u    // ymask [80][4] u64               = 640 floats

// ---- d_out layout (float offsets) ----
#define OUT0_OFF 0            // output [256,80]
#define PROB_OFF 20480        // scene_probs [256,6]
#define SEN_OUT  22016        // sample_en
#define BEN_OUT  22017        // batch_en
#define CMTS_OFF 22018        // comats [256,80,80]

// L1: fused. Blocks [0,320): Z = inp@W1. Block 320: ymask (ids-independent
// label bitmasks). Blocks [321, 321+131072): global max over 14x14.
__global__ __launch_bounds__(256) void k_pool_z(const float* __restrict__ x,
                                                float* __restrict__ img,
                                                const float* __restrict__ inp,
                                                const float* __restrict__ W1,
                                                float* __restrict__ Z,
                                                const float* __restrict__ y,
                                                unsigned long long* __restrict__ ym) {
    int tid = threadIdx.x;
    if (blockIdx.x < 320) {
        int c = blockIdx.x >> 2;
        int h = ((blockIdx.x & 3) << 8) + tid;
        float acc = 0.f;
        for (int e = 0; e < E_; e++) acc += inp[c * E_ + e] * W1[e * H_ + h];
        Z[c * H_ + h] = acc;
    } else if (blockIdx.x == 320) {
        // ymask[i][w]: bit (b&63) of word w = (y[b,i] != 0), b = tid
        int lane = tid & 63, wave = tid >> 6;
        const float4* yrow = (const float4*)(y + tid * 80);
#pragma unroll
        for (int q = 0; q < 20; q++) {
            float4 v = yrow[q];
            unsigned long long m0 = __ballot(v.x != 0.f);
            unsigned long long m1 = __ballot(v.y != 0.f);
            unsigned long long m2 = __ballot(v.z != 0.f);
            unsigned long long m3 = __ballot(v.w != 0.f);
            if (lane == 0) {
                ym[(q * 4 + 0) * 4 + wave] = m0;
                ym[(q * 4 + 1) * 4 + wave] = m1;
                ym[(q * 4 + 2) * 4 + wave] = m2;
                ym[(q * 4 + 3) * 4 + wave] = m3;
            }
        }
    } else {
        int pair = (blockIdx.x - 321) * 4 + (tid >> 6);
        int lane = tid & 63;
        const float4* xp = (const float4*)x + (size_t)pair * 49;
        float m = -INFINITY;
        if (lane < 49) {
            float4 v = xp[lane];
            m = fmaxf(fmaxf(v.x, v.y), fmaxf(v.z, v.w));
        }
#pragma unroll
        for (int off = 32; off >= 1; off >>= 1) m = fmaxf(m, __shfl_xor(m, off));
        if (lane == 0) img[pair] = m;
    }
}

// L2: fused. Blocks [0,256): scene softmax/argmax per b. Blocks [256,384):
// split-K=8 u-GEMM (u = img @ W2^T), 128x128 tile, 8x8 per-thread acc.
__global__ __launch_bounds__(256) void k_scene_ugemm(const float* __restrict__ img,
                                                     const float* __restrict__ Ws,
                                                     const float* __restrict__ W2,
                                                     float* __restrict__ probs_out,
                                                     int* __restrict__ ids,
                                                     float* __restrict__ part) {
    __shared__ float sm[2 * 16 * 132];
    int tid = threadIdx.x;
    if (blockIdx.x < 256) {
        float (*red)[256] = (float(*)[256])sm;
        int b = blockIdx.x;
        float acc[6] = {0, 0, 0, 0, 0, 0};
#pragma unroll
        for (int i = 0; i < 8; i++) {
            int f = tid + i * 256;
            float a = img[b * F_ + f];
#pragma unroll
            for (int s = 0; s < 6; s++) acc[s] += a * Ws[f * 6 + s];
        }
        for (int s = 0; s < 6; s++) red[s][tid] = acc[s];
        __syncthreads();
        for (int off = 128; off > 0; off >>= 1) {
            if (tid < off)
                for (int s = 0; s < 6; s++) red[s][tid] += red[s][tid + off];
            __syncthreads();
        }
        if (tid == 0) {
            float sc[6], mx = -INFINITY;
            for (int s = 0; s < 6; s++) { sc[s] = red[s][0]; mx = fmaxf(mx, sc[s]); }
            float sum = 0.f;
            for (int s = 0; s < 6; s++) { sc[s] = expf(sc[s] - mx); sum += sc[s]; }
            float inv = 1.0f / sum;
            int best = 0; float bv = -1.f;
            for (int s = 0; s < 6; s++) {
                float p = sc[s] * inv;
                probs_out[b * 6 + s] = p;
                if (p > bv) { bv = p; best = s; }
            }
            ids[b] = best;
        }
    } else {
        float* As = sm;
        float* Bs = sm + 16 * 132;
        int t = blockIdx.x - 256;
        int bx = t & 7, by = (t >> 3) & 1, bz = t >> 4;   // bz in [0,8)
        int m0 = by * 128, h0 = bx * 128;
        int kbase = bz * 256;
        float acc[8][8];
#pragma unroll
        for (int i = 0; i < 8; i++)
#pragma unroll
            for (int j = 0; j < 8; j++) acc[i][j] = 0.f;
        int r0 = (tid >> 4) << 3, c0 = (tid & 15) << 3;
        for (int st = 0; st < 16; st++) {
            int kc = kbase + st * 16;
#pragma unroll
            for (int l = 0; l < 2; l++) {
                int fid = tid + (l << 8);
                int r = fid >> 2, kq = fid & 3;
                float4 av = *(const float4*)(img + (size_t)(m0 + r) * 2048 + kc + (kq << 2));
                float4 bv = *(const float4*)(W2 + (size_t)(h0 + r) * 2048 + kc + (kq << 2));
                int kk = kq << 2;
                As[(kk + 0) * 132 + r] = av.x; As[(kk + 1) * 132 + r] = av.y;
                As[(kk + 2) * 132 + r] = av.z; As[(kk + 3) * 132 + r] = av.w;
                Bs[(kk + 0) * 132 + r] = bv.x; Bs[(kk + 1) * 132 + r] = bv.y;
                Bs[(kk + 2) * 132 + r] = bv.z; Bs[(kk + 3) * 132 + r] = bv.w;
            }
            __syncthreads();
#pragma unroll
            for (int k = 0; k < 16; k++) {
                float4 a0 = *(const float4*)&As[k * 132 + r0];
                float4 a1 = *(const float4*)&As[k * 132 + r0 + 4];
                float4 b0 = *(const float4*)&Bs[k * 132 + c0];
                float4 b1 = *(const float4*)&Bs[k * 132 + c0 + 4];
                float ar[8] = {a0.x, a0.y, a0.z, a0.w, a1.x, a1.y, a1.z, a1.w};
                float br[8] = {b0.x, b0.y, b0.z, b0.w, b1.x, b1.y, b1.z, b1.w};
#pragma unroll
                for (int i = 0; i < 8; i++)
#pragma unroll
                    for (int j = 0; j < 8; j++) acc[i][j] += ar[i] * br[j];
            }
            __syncthreads();
        }
        float* pu = part + (size_t)bz * 262144;
#pragma unroll
        for (int i = 0; i < 8; i++) {
            int row = m0 + r0 + i;
            float4 v0 = {acc[i][0], acc[i][1], acc[i][2], acc[i][3]};
            float4 v1 = {acc[i][4], acc[i][5], acc[i][6], acc[i][7]};
            *(float4*)(pu + (size_t)row * 1024 + h0 + c0) = v0;
            *(float4*)(pu + (size_t)row * 1024 + h0 + c0 + 4) = v1;
        }
    }
}

// L3: graph kernel. Per-block comat recompute is now mask algebra:
// count_s[i][j] = popcount(ymask_i & ymask_j & smask_s); smask = 4 ballots.
//   blocks [0,480):   (s,c): adjA row c of scene s + g[s,c,:] = LReLU(row@Z)
//   blocks [480,736): b: cmts[b] = normalized comat of scene ids[b]
//   block 736:        entropy finalization from probs
__global__ __launch_bounds__(256) void k_graph(const unsigned long long* __restrict__ ym,
                                               const float* __restrict__ cm_in,
                                               const int* __restrict__ ids,
                                               const float* __restrict__ Z,
                                               const float* __restrict__ probs,
                                               float* __restrict__ adjA,
                                               float* __restrict__ g,
                                               float* __restrict__ cmts,
                                               float* __restrict__ o_sen,
                                               float* __restrict__ o_ben) {
    int tid = threadIdx.x;
    if (blockIdx.x == 736) {
        if (tid < 64) {
            float lent = 0.f;
            float lp[6] = {0, 0, 0, 0, 0, 0};
            for (int i = 0; i < 4; i++) {
                int b = tid * 4 + i;
#pragma unroll
                for (int s = 0; s < 6; s++) {
                    float p = probs[b * 6 + s];
                    lp[s] += p;
                    lent -= p * logf(p + EPS_);
                }
            }
#pragma unroll
            for (int off = 32; off >= 1; off >>= 1) {
                lent += __shfl_xor(lent, off);
#pragma unroll
                for (int s = 0; s < 6; s++) lp[s] += __shfl_xor(lp[s], off);
            }
            if (tid == 0) {
                *o_sen = lent / 256.0f;
                float ent = 0.f;
                for (int s = 0; s < 6; s++) {
                    float q = lp[s] / 256.0f;
                    ent -= q * logf(q + EPS_);
                }
                float invS = 1.0f / 6.0f;
                float men = -6.0f * (invS * logf(invS + EPS_));
                *o_ben = (men - ent) * 100.0f;
            }
        }
        return;
    }
    __shared__ unsigned long long colq[80][4];
    __shared__ unsigned long long smask[4];
    __shared__ float cm[6400];
    __shared__ float diag[80], Dn[80], arow[80];
    bool isG = blockIdx.x < 480;
    int s, c = 0, b = 0;
    if (isG) { s = blockIdx.x / 80; c = blockIdx.x % 80; }
    else { b = blockIdx.x - 480; s = ids[b]; }
    int lane = tid & 63, wave = tid >> 6;
    unsigned long long smw = __ballot(ids[tid] == s);
    if (lane == 0) smask[wave] = smw;
    __syncthreads();
    for (int p = tid; p < 320; p += 256)
        colq[p >> 2][p & 3] = ym[p] & smask[p & 3];
    __syncthreads();
    for (int p = tid; p < 6400; p += 256) {
        int i = p / 80, j = p - i * 80;
        int cnt = 0;
#pragma unroll
        for (int w = 0; w < 4; w++) cnt += __popcll(colq[i][w] & colq[j][w]);
        cm[p] = cm_in[s * 6400 + p] + (float)cnt;
    }
    __syncthreads();
    if (tid < 80) diag[tid] = cm[tid * 81];
    __syncthreads();
    for (int p = tid; p < 6400; p += 256) {
        int i = p / 80, j = p - i * 80;
        cm[p] = (i == j) ? 1.0f : cm[p] / (diag[i] + DEPS_);
    }
    __syncthreads();
    if (!isG) {
        const float2* src = (const float2*)cm;
        float2* dst = (float2*)(cmts + (size_t)b * 6400);
        for (int i = tid; i < 3200; i += 256) dst[i] = src[i];
        return;
    }
    if (tid < 80) {
        float rs = 0.f;
        for (int j = 0; j < 80; j++) rs += cm[tid * 80 + j];
        Dn[tid] = 1.0f / sqrtf(rs);
    }
    __syncthreads();
    if (tid < 80) {
        float v = Dn[c] * cm[tid * 80 + c] * Dn[tid];
        arow[tid] = v;
        adjA[(s * 80 + c) * 80 + tid] = v;
    }
    __syncthreads();
    const float4* Z4 = (const float4*)Z;
    float4 acc = {0, 0, 0, 0};
    for (int j = 0; j < 80; j++) {
        float a = arow[j];
        float4 z = Z4[j * 256 + tid];
        acc.x += a * z.x; acc.y += a * z.y; acc.z += a * z.z; acc.w += a * z.w;
    }
    acc.x = acc.x > 0.f ? acc.x : LEAK_ * acc.x;
    acc.y = acc.y > 0.f ? acc.y : LEAK_ * acc.y;
    acc.z = acc.z > 0.f ? acc.z : LEAK_ * acc.z;
    acc.w = acc.w > 0.f ? acc.w : LEAK_ * acc.w;
    ((float4*)g)[(s * 80 + c) * 256 + tid] = acc;
}

// L4: per-b: u[b] = sum of 8 partials; t = g[s]@u; out[b] = adjA[s]@t.
__global__ __launch_bounds__(320) void k_out(const float* __restrict__ part,
                                             const float* __restrict__ g,
                                             const float* __restrict__ adjA,
                                             const int* __restrict__ ids,
                                             float* __restrict__ out0) {
    __shared__ float ul[1024];
    __shared__ float tp[320];
    __shared__ float tv[80];
    int b = blockIdx.x, tid = threadIdx.x;
    int s = ids[b];
    for (int h = tid; h < 1024; h += 320) {
        float a = 0.f;
#pragma unroll
        for (int z = 0; z < 8; z++) a += part[z * 262144 + b * 1024 + h];
        ul[h] = a;
    }
    __syncthreads();
    int c = tid >> 2, q = tid & 3;
    const float4* gp = (const float4*)(g + (s * 80 + c) * 1024 + q * 256);
    const float4* up = (const float4*)(ul + q * 256);
    float a = 0.f;
    for (int k = 0; k < 64; k++) {
        float4 gv = gp[k];
        float4 uv = up[k];
        a += gv.x * uv.x + gv.y * uv.y + gv.z * uv.z + gv.w * uv.w;
    }
    tp[tid] = a;
    __syncthreads();
    if (tid < 80) tv[tid] = tp[tid * 4] + tp[tid * 4 + 1] + tp[tid * 4 + 2] + tp[tid * 4 + 3];
    __syncthreads();
    if (tid < 80) {
        const float* ar = adjA + (s * 80 + tid) * 80;
        float o = 0.f;
        for (int j = 0; j < 80; j++) o += ar[j] * tv[j];
        out0[b * 80 + tid] = o;
    }
}

extern "C" void kernel_launch(void* const* d_in, const int* in_sizes, int n_in,
                              void* d_out, int out_size, void* d_ws, size_t ws_size,
                              hipStream_t stream) {
    const float* x    = (const float*)d_in[0];
    const float* inp  = (const float*)d_in[1];
    const float* y    = (const float*)d_in[2];
    const float* cmin = (const float*)d_in[3];
    const float* Ws   = (const float*)d_in[4];
    const float* W1   = (const float*)d_in[5];
    const float* W2   = (const float*)d_in[6];
    float* out = (float*)d_out;
    float* W = (float*)d_ws;

    float* img   = W + IMG_OFF;
    float* Z     = W + Z_OFF;
    float* adjA  = W + ADJA_OFF;
    float* g     = W + G_OFF;
    float* part  = W + PART_OFF;
    int*   ids   = (int*)(W + IDS_OFF);
    unsigned long long* ym = (unsigned long long*)(W + YM_OFF);

    k_pool_z<<<131393, 256, 0, stream>>>(x, img, inp, W1, Z, y, ym);
    k_scene_ugemm<<<384, 256, 0, stream>>>(img, Ws, W2, out + PROB_OFF, ids, part);
    k_graph<<<737, 256, 0, stream>>>(ym, cmin, ids, Z, out + PROB_OFF, adjA, g,
                                     out + CMTS_OFF, out + SEN_OUT, out + BEN_OUT);
    k_out<<<256, 320, 0, stream>>>(part, g, adjA, ids, out + OUT0_OFF);
}

// Round 4
// 606.047 us; speedup vs baseline: 1.0435x; 1.0186x over previous
//
#include <hip/hip_runtime.h>
#include <math.h>

#define B_ 256
#define S_ 6
#define C_ 80
#define F_ 2048
#define E_ 300
#define H_ 1024
#define EPS_ 1e-7f
#define DEPS_ 1e-8f
#define LEAK_ 0.2f

// ---- ws layout (float offsets) ----
#define IMG_OFF   0u          // img_feats [256,2048]            = 524288
#define Z_OFF     524288u     // Z = inp@W1 [80,1024]            = 81920
#define ADJA_OFF  644608u     // adjA [6,80,80]                  = 38400
#define G_OFF     683008u     // g = LReLU(adjA@Z) [6,80,1024]   = 491520
#define PART_OFF  1174528u    // u partials [8][256,1024]        = 2097152
#define IDS_OFF   5368832u    // ids [256] (int)                 = 256
#define YM_OFF    5369088u    // ymask [80][4] u64               = 640 floats

// ---- d_out layout (float offsets) ----
#define OUT0_OFF 0            // output [256,80]
#define PROB_OFF 20480        // scene_probs [256,6]
#define SEN_OUT  22016        // sample_en
#define BEN_OUT  22017        // batch_en
#define CMTS_OFF 22018        // comats [256,80,80]

// L1: fused. Blocks [0,320): Z = inp@W1. Block 320: ymask (ids-independent
// label bitmasks). Blocks [321, 321+131072): global max over 14x14.
__global__ __launch_bounds__(256) void k_pool_z(const float* __restrict__ x,
                                                float* __restrict__ img,
                                                const float* __restrict__ inp,
                                                const float* __restrict__ W1,
                                                float* __restrict__ Z,
                                                const float* __restrict__ y,
                                                unsigned long long* __restrict__ ym) {
    int tid = threadIdx.x;
    if (blockIdx.x < 320) {
        int c = blockIdx.x >> 2;
        int h = ((blockIdx.x & 3) << 8) + tid;
        float acc = 0.f;
        for (int e = 0; e < E_; e++) acc += inp[c * E_ + e] * W1[e * H_ + h];
        Z[c * H_ + h] = acc;
    } else if (blockIdx.x == 320) {
        int lane = tid & 63, wave = tid >> 6;
        const float4* yrow = (const float4*)(y + tid * 80);
#pragma unroll
        for (int q = 0; q < 20; q++) {
            float4 v = yrow[q];
            unsigned long long m0 = __ballot(v.x != 0.f);
            unsigned long long m1 = __ballot(v.y != 0.f);
            unsigned long long m2 = __ballot(v.z != 0.f);
            unsigned long long m3 = __ballot(v.w != 0.f);
            if (lane == 0) {
                ym[(q * 4 + 0) * 4 + wave] = m0;
                ym[(q * 4 + 1) * 4 + wave] = m1;
                ym[(q * 4 + 2) * 4 + wave] = m2;
                ym[(q * 4 + 3) * 4 + wave] = m3;
            }
        }
    } else {
        int pair = (blockIdx.x - 321) * 4 + (tid >> 6);
        int lane = tid & 63;
        const float4* xp = (const float4*)x + (size_t)pair * 49;
        float m = -INFINITY;
        if (lane < 49) {
            float4 v = xp[lane];
            m = fmaxf(fmaxf(v.x, v.y), fmaxf(v.z, v.w));
        }
#pragma unroll
        for (int off = 32; off >= 1; off >>= 1) m = fmaxf(m, __shfl_xor(m, off));
        if (lane == 0) img[pair] = m;
    }
}

// L2: fused. Blocks [0,256): scene softmax/argmax per b. Blocks [256,768):
// split-K=8 u-GEMM (u = img @ W2^T), 64x64 tile, 4x4 per-thread acc.
// 64x64 tiling quarters the per-block serial FMA chain vs 128x128
// (4096 vs 16384 FMA/thread) and fills all CUs (768 blocks total).
__global__ __launch_bounds__(256) void k_scene_ugemm(const float* __restrict__ img,
                                                     const float* __restrict__ Ws,
                                                     const float* __restrict__ W2,
                                                     float* __restrict__ probs_out,
                                                     int* __restrict__ ids,
                                                     float* __restrict__ part) {
    __shared__ float sm[2 * 16 * 68];    // 8.7 KB; scene branch uses 6*256 of it
    int tid = threadIdx.x;
    if (blockIdx.x < 256) {
        float (*red)[256] = (float(*)[256])sm;
        int b = blockIdx.x;
        float acc[6] = {0, 0, 0, 0, 0, 0};
#pragma unroll
        for (int i = 0; i < 8; i++) {
            int f = tid + i * 256;
            float a = img[b * F_ + f];
#pragma unroll
            for (int s = 0; s < 6; s++) acc[s] += a * Ws[f * 6 + s];
        }
        for (int s = 0; s < 6; s++) red[s][tid] = acc[s];
        __syncthreads();
        for (int off = 128; off > 0; off >>= 1) {
            if (tid < off)
                for (int s = 0; s < 6; s++) red[s][tid] += red[s][tid + off];
            __syncthreads();
        }
        if (tid == 0) {
            float sc[6], mx = -INFINITY;
            for (int s = 0; s < 6; s++) { sc[s] = red[s][0]; mx = fmaxf(mx, sc[s]); }
            float sum = 0.f;
            for (int s = 0; s < 6; s++) { sc[s] = expf(sc[s] - mx); sum += sc[s]; }
            float inv = 1.0f / sum;
            int best = 0; float bv = -1.f;
            for (int s = 0; s < 6; s++) {
                float p = sc[s] * inv;
                probs_out[b * 6 + s] = p;
                if (p > bv) { bv = p; best = s; }
            }
            ids[b] = best;
        }
    } else {
        float* As = sm;
        float* Bs = sm + 16 * 68;
        int t = blockIdx.x - 256;            // [0,512)
        int bx = t & 15, by = (t >> 4) & 3, bz = t >> 6;   // N=16, M=4, K=8
        int m0 = by * 64, h0 = bx * 64;
        int kbase = bz * 256;
        float acc[4][4];
#pragma unroll
        for (int i = 0; i < 4; i++)
#pragma unroll
            for (int j = 0; j < 4; j++) acc[i][j] = 0.f;
        int r0 = (tid >> 4) << 2, c0 = (tid & 15) << 2;
        int sr = tid >> 2, skq = tid & 3;    // staging: row, k-quad
        for (int st = 0; st < 16; st++) {
            int kc = kbase + st * 16;
            float4 av = *(const float4*)(img + (size_t)(m0 + sr) * 2048 + kc + (skq << 2));
            float4 bv = *(const float4*)(W2 + (size_t)(h0 + sr) * 2048 + kc + (skq << 2));
            int kk = skq << 2;
            As[(kk + 0) * 68 + sr] = av.x; As[(kk + 1) * 68 + sr] = av.y;
            As[(kk + 2) * 68 + sr] = av.z; As[(kk + 3) * 68 + sr] = av.w;
            Bs[(kk + 0) * 68 + sr] = bv.x; Bs[(kk + 1) * 68 + sr] = bv.y;
            Bs[(kk + 2) * 68 + sr] = bv.z; Bs[(kk + 3) * 68 + sr] = bv.w;
            __syncthreads();
#pragma unroll
            for (int k = 0; k < 16; k++) {
                float4 a0 = *(const float4*)&As[k * 68 + r0];
                float4 b0 = *(const float4*)&Bs[k * 68 + c0];
                float ar[4] = {a0.x, a0.y, a0.z, a0.w};
                float br[4] = {b0.x, b0.y, b0.z, b0.w};
#pragma unroll
                for (int i = 0; i < 4; i++)
#pragma unroll
                    for (int j = 0; j < 4; j++) acc[i][j] += ar[i] * br[j];
            }
            __syncthreads();
        }
        float* pu = part + (size_t)bz * 262144;
#pragma unroll
        for (int i = 0; i < 4; i++) {
            int row = m0 + r0 + i;
            float4 v0 = {acc[i][0], acc[i][1], acc[i][2], acc[i][3]};
            *(float4*)(pu + (size_t)row * 1024 + h0 + c0) = v0;
        }
    }
}

// L3: graph kernel. Per-block comat recompute is mask algebra:
// count_s[i][j] = popcount(ymask_i & ymask_j & smask_s); smask = 4 ballots.
//   blocks [0,480):   (s,c): adjA row c of scene s + g[s,c,:] = LReLU(row@Z)
//   blocks [480,736): b: cmts[b] = normalized comat of scene ids[b]
//   block 736:        entropy finalization from probs
__global__ __launch_bounds__(256) void k_graph(const unsigned long long* __restrict__ ym,
                                               const float* __restrict__ cm_in,
                                               const int* __restrict__ ids,
                                               const float* __restrict__ Z,
                                               const float* __restrict__ probs,
                                               float* __restrict__ adjA,
                                               float* __restrict__ g,
                                               float* __restrict__ cmts,
                                               float* __restrict__ o_sen,
                                               float* __restrict__ o_ben) {
    int tid = threadIdx.x;
    if (blockIdx.x == 736) {
        if (tid < 64) {
            float lent = 0.f;
            float lp[6] = {0, 0, 0, 0, 0, 0};
            for (int i = 0; i < 4; i++) {
                int b = tid * 4 + i;
#pragma unroll
                for (int s = 0; s < 6; s++) {
                    float p = probs[b * 6 + s];
                    lp[s] += p;
                    lent -= p * logf(p + EPS_);
                }
            }
#pragma unroll
            for (int off = 32; off >= 1; off >>= 1) {
                lent += __shfl_xor(lent, off);
#pragma unroll
                for (int s = 0; s < 6; s++) lp[s] += __shfl_xor(lp[s], off);
            }
            if (tid == 0) {
                *o_sen = lent / 256.0f;
                float ent = 0.f;
                for (int s = 0; s < 6; s++) {
                    float q = lp[s] / 256.0f;
                    ent -= q * logf(q + EPS_);
                }
                float invS = 1.0f / 6.0f;
                float men = -6.0f * (invS * logf(invS + EPS_));
                *o_ben = (men - ent) * 100.0f;
            }
        }
        return;
    }
    __shared__ unsigned long long colq[80][4];
    __shared__ unsigned long long smask[4];
    __shared__ float cm[6400];
    __shared__ float diag[80], Dn[80], arow[80];
    bool isG = blockIdx.x < 480;
    int s, c = 0, b = 0;
    if (isG) { s = blockIdx.x / 80; c = blockIdx.x % 80; }
    else { b = blockIdx.x - 480; s = ids[b]; }
    int lane = tid & 63, wave = tid >> 6;
    unsigned long long smw = __ballot(ids[tid] == s);
    if (lane == 0) smask[wave] = smw;
    __syncthreads();
    for (int p = tid; p < 320; p += 256)
        colq[p >> 2][p & 3] = ym[p] & smask[p & 3];
    __syncthreads();
    for (int p = tid; p < 6400; p += 256) {
        int i = p / 80, j = p - i * 80;
        int cnt = 0;
#pragma unroll
        for (int w = 0; w < 4; w++) cnt += __popcll(colq[i][w] & colq[j][w]);
        cm[p] = cm_in[s * 6400 + p] + (float)cnt;
    }
    __syncthreads();
    if (tid < 80) diag[tid] = cm[tid * 81];
    __syncthreads();
    for (int p = tid; p < 6400; p += 256) {
        int i = p / 80, j = p - i * 80;
        cm[p] = (i == j) ? 1.0f : cm[p] / (diag[i] + DEPS_);
    }
    __syncthreads();
    if (!isG) {
        const float2* src = (const float2*)cm;
        float2* dst = (float2*)(cmts + (size_t)b * 6400);
        for (int i = tid; i < 3200; i += 256) dst[i] = src[i];
        return;
    }
    if (tid < 80) {
        float rs = 0.f;
        for (int j = 0; j < 80; j++) rs += cm[tid * 80 + j];
        Dn[tid] = 1.0f / sqrtf(rs);
    }
    __syncthreads();
    if (tid < 80) {
        float v = Dn[c] * cm[tid * 80 + c] * Dn[tid];
        arow[tid] = v;
        adjA[(s * 80 + c) * 80 + tid] = v;
    }
    __syncthreads();
    const float4* Z4 = (const float4*)Z;
    float4 acc = {0, 0, 0, 0};
    for (int j = 0; j < 80; j++) {
        float a = arow[j];
        float4 z = Z4[j * 256 + tid];
        acc.x += a * z.x; acc.y += a * z.y; acc.z += a * z.z; acc.w += a * z.w;
    }
    acc.x = acc.x > 0.f ? acc.x : LEAK_ * acc.x;
    acc.y = acc.y > 0.f ? acc.y : LEAK_ * acc.y;
    acc.z = acc.z > 0.f ? acc.z : LEAK_ * acc.z;
    acc.w = acc.w > 0.f ? acc.w : LEAK_ * acc.w;
    ((float4*)g)[(s * 80 + c) * 256 + tid] = acc;
}

// L4: per-b: u[b] = sum of 8 partials; t = g[s]@u; out[b] = adjA[s]@t.
__global__ __launch_bounds__(320) void k_out(const float* __restrict__ part,
                                             const float* __restrict__ g,
                                             const float* __restrict__ adjA,
                                             const int* __restrict__ ids,
                                             float* __restrict__ out0) {
    __shared__ float ul[1024];
    __shared__ float tp[320];
    __shared__ float tv[80];
    int b = blockIdx.x, tid = threadIdx.x;
    int s = ids[b];
    for (int h = tid; h < 1024; h += 320) {
        float a = 0.f;
#pragma unroll
        for (int z = 0; z < 8; z++) a += part[z * 262144 + b * 1024 + h];
        ul[h] = a;
    }
    __syncthreads();
    int c = tid >> 2, q = tid & 3;
    const float4* gp = (const float4*)(g + (s * 80 + c) * 1024 + q * 256);
    const float4* up = (const float4*)(ul + q * 256);
    float a = 0.f;
    for (int k = 0; k < 64; k++) {
        float4 gv = gp[k];
        float4 uv = up[k];
        a += gv.x * uv.x + gv.y * uv.y + gv.z * uv.z + gv.w * uv.w;
    }
    tp[tid] = a;
    __syncthreads();
    if (tid < 80) tv[tid] = tp[tid * 4] + tp[tid * 4 + 1] + tp[tid * 4 + 2] + tp[tid * 4 + 3];
    __syncthreads();
    if (tid < 80) {
        const float* ar = adjA + (s * 80 + tid) * 80;
        float o = 0.f;
        for (int j = 0; j < 80; j++) o += ar[j] * tv[j];
        out0[b * 80 + tid] = o;
    }
}

extern "C" void kernel_launch(void* const* d_in, const int* in_sizes, int n_in,
                              void* d_out, int out_size, void* d_ws, size_t ws_size,
                              hipStream_t stream) {
    const float* x    = (const float*)d_in[0];
    const float* inp  = (const float*)d_in[1];
    const float* y    = (const float*)d_in[2];
    const float* cmin = (const float*)d_in[3];
    const float* Ws   = (const float*)d_in[4];
    const float* W1   = (const float*)d_in[5];
    const float* W2   = (const float*)d_in[6];
    float* out = (float*)d_out;
    float* W = (float*)d_ws;

    float* img   = W + IMG_OFF;
    float* Z     = W + Z_OFF;
    float* adjA  = W + ADJA_OFF;
    float* g     = W + G_OFF;
    float* part  = W + PART_OFF;
    int*   ids   = (int*)(W + IDS_OFF);
    unsigned long long* ym = (unsigned long long*)(W + YM_OFF);

    k_pool_z<<<131393, 256, 0, stream>>>(x, img, inp, W1, Z, y, ym);
    k_scene_ugemm<<<768, 256, 0, stream>>>(img, Ws, W2, out + PROB_OFF, ids, part);
    k_graph<<<737, 256, 0, stream>>>(ym, cmin, ids, Z, out + PROB_OFF, adjA, g,
                                     out + CMTS_OFF, out + SEN_OUT, out + BEN_OUT);
    k_out<<<256, 320, 0, stream>>>(part, g, adjA, ids, out + OUT0_OFF);
}